// Round 15
// baseline (607.624 us; speedup 1.0000x reference)
//
#include <hip/hip_runtime.h>
#include <math.h>

// Problem constants
#define NN 118   // nodes
#define EE 372   // edges
#define GG 2048  // B*T
#define DD 128   // hidden
#define TT 256   // seq len
#define BB 8     // batch
#define FD 512   // 4*D

// LDS strides (bf16 elems; rows 16B-aligned)
#define XS 136   // xb2 row stride
#define MS 264   // hS2 row stride

typedef short bf16x8 __attribute__((ext_vector_type(8)));
typedef float f32x4  __attribute__((ext_vector_type(4)));
typedef _Float16 f16x2 __attribute__((ext_vector_type(2)));

__device__ __forceinline__ float frcp_(float x) { return __builtin_amdgcn_rcpf(x); }
__device__ __forceinline__ float sig_f(float x) { return frcp_(1.0f + __expf(-x)); }
__device__ __forceinline__ float tanh_f(float x) { return 1.0f - 2.0f * frcp_(__expf(2.0f * x) + 1.0f); }
__device__ __forceinline__ float silu_f(float x) { return x * frcp_(1.0f + __expf(-x)); }
__device__ __forceinline__ float siluf_(float x) { return x / (1.0f + expf(-x)); }

// f16-pair dot with fp32 accumulate (v_dot2_f32_f16); scalar fallback.
__device__ __forceinline__ float fdot2_(unsigned int a, unsigned int b, float c) {
#if defined(__has_builtin) && __has_builtin(__builtin_amdgcn_fdot2)
    return __builtin_amdgcn_fdot2(__builtin_bit_cast(f16x2, a),
                                  __builtin_bit_cast(f16x2, b), c, false);
#else
    f16x2 x = __builtin_bit_cast(f16x2, a), y = __builtin_bit_cast(f16x2, b);
    return c + (float)x[0] * (float)y[0] + (float)x[1] * (float)y[1];
#endif
}

// Barrier draining only LDS ops (lgkmcnt), not vmcnt.
__device__ __forceinline__ void bar_lds() {
    asm volatile("s_waitcnt lgkmcnt(0)\n\ts_barrier" ::: "memory");
}

__device__ __forceinline__ unsigned short f2bf(float x) {
    unsigned int u = __float_as_uint(x);
    unsigned int r = (u + 0x7fffu + ((u >> 16) & 1u)) >> 16;
    return (unsigned short)r;
}
__device__ __forceinline__ float bf2f(unsigned short b) {
    return __uint_as_float(((unsigned int)b) << 16);
}
__device__ __forceinline__ unsigned int packf16(float a, float b) {
    unsigned short lo = __builtin_bit_cast(unsigned short, (_Float16)a);
    unsigned short hi = __builtin_bit_cast(unsigned short, (_Float16)b);
    return (unsigned int)lo | ((unsigned int)hi << 16);
}

// ---------------------------------------------------------------------------
// prep: dense normalized adjacency A -> bf16 128x128 (zero padded), fused
// LSTM biases. 1 block.
// ---------------------------------------------------------------------------
__global__ void prep_kernel(const int* __restrict__ ei,
                            const float* __restrict__ bih0, const float* __restrict__ bhh0,
                            const float* __restrict__ bih1, const float* __restrict__ bhh1,
                            float* __restrict__ bias0, float* __restrict__ bias1,
                            unsigned short* __restrict__ AbG) {
    __shared__ int sflag;
    __shared__ int ssrc[EE], sdst[EE];
    __shared__ int scount[NN];
    __shared__ float sinv[NN];
    __shared__ float Adense[NN * NN];  // 55.7 KB
    int tid = threadIdx.x;
    if (tid == 0) sflag = 0;
    __syncthreads();
    for (int i = tid; i < 2 * EE; i += blockDim.x)
        if ((i & 1) && ei[i] != 0) atomicOr(&sflag, 1);
    __syncthreads();
    bool m64 = (sflag == 0);
    for (int e = tid; e < EE; e += blockDim.x) {
        int s, d;
        if (m64) { s = ei[2 * e]; d = ei[2 * EE + 2 * e]; }
        else     { s = ei[e];     d = ei[EE + e]; }
        s = min(max(s, 0), NN - 1); d = min(max(d, 0), NN - 1);
        ssrc[e] = s; sdst[e] = d;
    }
    for (int n = tid; n < NN; n += blockDim.x) scount[n] = 0;
    for (int i = tid; i < NN * NN; i += blockDim.x) Adense[i] = 0.0f;
    __syncthreads();
    for (int e = tid; e < EE; e += blockDim.x) atomicAdd(&scount[sdst[e]], 1);
    __syncthreads();
    for (int n = tid; n < NN; n += blockDim.x) {
        float deg = 1.0f + (float)scount[n];
        sinv[n] = rsqrtf(deg);
        Adense[n * NN + n] = 1.0f / deg;   // self term h*(1/deg)
    }
    __syncthreads();
    for (int e = tid; e < EE; e += blockDim.x)
        atomicAdd(&Adense[sdst[e] * NN + ssrc[e]], sinv[ssrc[e]] * sinv[sdst[e]]);
    __syncthreads();
    for (int i = tid; i < 128 * 128; i += blockDim.x) {
        int r = i >> 7, c = i & 127;
        AbG[i] = (r < NN && c < NN) ? f2bf(Adense[r * NN + c]) : (unsigned short)0;
    }
    for (int j = tid; j < FD; j += blockDim.x) {
        bias0[j] = bih0[j] + bhh0[j];
        bias1[j] = bih1[j] + bhh1[j];
    }
}

// ---------------------------------------------------------------------------
// convall: all weight reformats in ONE launch (384 blocks x 512):
//  blocks   0..31 : W2 -> Wt2g bf16 [n][k]
//  blocks  32..63 : W3 -> Wt3g bf16 [n][k]
//  blocks  64..127: Whh0 -> Wc0 f16 pairs, r11 K-split-4 layout
//  blocks 128..255: [Wih1|Whh1] -> Wc1 f16 pairs, combined-K=256 split-4
//  blocks 256..383: Wih0 -> WT0 [k][j] fp32 (proj0 reads coalesced)
// ---------------------------------------------------------------------------
__global__ void convall_kernel(const float* __restrict__ W2, const float* __restrict__ W3,
                               const float* __restrict__ Whh0,
                               const float* __restrict__ Wih1, const float* __restrict__ Whh1,
                               const float* __restrict__ Wih0,
                               unsigned short* __restrict__ Wt2g, unsigned short* __restrict__ Wt3g,
                               unsigned int* __restrict__ Wc0, unsigned int* __restrict__ Wc1,
                               float* __restrict__ WT0) {
    int bid = blockIdx.x, tid = threadIdx.x;
    if (bid < 64) {
        const float* W = (bid < 32) ? W2 : W3;
        unsigned short* out = (bid < 32) ? Wt2g : Wt3g;
        int i = (bid & 31) * 512 + tid;            // 16384 total
        int n = i >> 7, k = i & 127;
        out[i] = f2bf(W[k * DD + n]);
    } else if (bid < 128) {
        int i = (bid - 64) * 512 + tid;            // 32768 total
        int d = i & 127;
        int rest = i >> 7;
        int quarter = rest & 3;
        int qg = rest >> 2;
        int q = qg & 15, g = qg >> 4;
        const float* row = Whh0 + (size_t)(g * 128 + d) * 128 + quarter * 32;
        Wc0[i] = packf16(row[2 * q], row[2 * q + 1]);
    } else if (bid < 256) {
        int i = (bid - 128) * 512 + tid;           // 65536 total
        int d = i & 127;
        int rest = i >> 7;                          // 0..511
        int quarter = rest & 3;
        int qg = rest >> 2;                         // 0..127
        int q = qg & 31, g = qg >> 5;
        int kk = quarter * 64 + 2 * q;              // combined K index (0..254, even)
        float a, b;
        if (kk < 128) {
            const float* row = Wih1 + (size_t)(g * 128 + d) * 128;
            a = row[kk]; b = row[kk + 1];
        } else {
            const float* row = Whh1 + (size_t)(g * 128 + d) * 128;
            a = row[kk - 128]; b = row[kk - 127];
        }
        Wc1[i] = packf16(a, b);
    } else {
        int idx = (bid - 256) * 512 + tid;         // 65536 total
        int j = idx >> 7, k = idx & 127;
        WT0[k * FD + j] = Wih0[idx];
    }
}

// ---------------------------------------------------------------------------
// GCN, two graphs per block (round-14 version, unchanged)
// ---------------------------------------------------------------------------
__device__ __forceinline__ void mm_agg2(const unsigned short* __restrict__ AbG,
                                        const unsigned short* __restrict__ hS2,
                                        unsigned short* __restrict__ xb2,
                                        const float* __restrict__ bias,
                                        int gr, int wm, int wn, int lm, int lq) {
    f32x4 acc[4][4];
#pragma unroll
    for (int mt = 0; mt < 4; ++mt)
#pragma unroll
        for (int nt = 0; nt < 4; ++nt) acc[mt][nt] = (f32x4){0.f, 0.f, 0.f, 0.f};
#pragma unroll
    for (int kb = 0; kb < 4; ++kb) {
        int ko = kb * 32 + lq * 8;
        bf16x8 bfr[4];
#pragma unroll
        for (int nt = 0; nt < 4; ++nt)
            bfr[nt] = *(const bf16x8*)(hS2 + (wn + nt * 16 + lm) * MS + gr * 128 + ko);
#pragma unroll
        for (int mt = 0; mt < 4; ++mt) {
            bf16x8 af = *(const bf16x8*)(AbG + (wm + mt * 16 + lm) * 128 + ko);
#pragma unroll
            for (int nt = 0; nt < 4; ++nt)
                acc[mt][nt] = __builtin_amdgcn_mfma_f32_16x16x32_bf16(af, bfr[nt], acc[mt][nt], 0, 0, 0);
        }
    }
#pragma unroll
    for (int nt = 0; nt < 4; ++nt) {
        float bn = bias[wn + nt * 16 + lm];
        int col = wn + nt * 16 + lm;
#pragma unroll
        for (int mt = 0; mt < 4; ++mt)
#pragma unroll
            for (int i = 0; i < 4; ++i) {
                float v = silu_f(acc[mt][nt][i] + bn);
                xb2[(gr * 128 + wm + mt * 16 + lq * 4 + i) * XS + col] = f2bf(v);
            }
    }
}

__device__ __forceinline__ void mm_xw2(const unsigned short* __restrict__ xb2,
                                       const unsigned short* __restrict__ WtG,
                                       unsigned short* __restrict__ hS2,
                                       int gr, int wm, int wn, int lm, int lq) {
    f32x4 acc[4][4];
#pragma unroll
    for (int mt = 0; mt < 4; ++mt)
#pragma unroll
        for (int nt = 0; nt < 4; ++nt) acc[mt][nt] = (f32x4){0.f, 0.f, 0.f, 0.f};
#pragma unroll
    for (int kb = 0; kb < 4; ++kb) {
        int ko = kb * 32 + lq * 8;
        bf16x8 bfr[4];
#pragma unroll
        for (int nt = 0; nt < 4; ++nt)
            bfr[nt] = *(const bf16x8*)(WtG + (wn + nt * 16 + lm) * 128 + ko);
#pragma unroll
        for (int mt = 0; mt < 4; ++mt) {
            bf16x8 af = *(const bf16x8*)(xb2 + (gr * 128 + wm + mt * 16 + lm) * XS + ko);
#pragma unroll
            for (int nt = 0; nt < 4; ++nt)
                acc[mt][nt] = __builtin_amdgcn_mfma_f32_16x16x32_bf16(af, bfr[nt], acc[mt][nt], 0, 0, 0);
        }
    }
#pragma unroll
    for (int nt = 0; nt < 4; ++nt)
#pragma unroll
        for (int mt = 0; mt < 4; ++mt) {
            f32x4 a = acc[mt][nt];
            ushort4 pk;
            pk.x = f2bf(a[0]); pk.y = f2bf(a[1]); pk.z = f2bf(a[2]); pk.w = f2bf(a[3]);
            *(ushort4*)(hS2 + (wn + nt * 16 + lm) * MS + gr * 128 + wm + mt * 16 + lq * 4) = pk;
        }
}

__global__ __launch_bounds__(512, 2) void gcn_kernel(
    const float* __restrict__ xg, const float* __restrict__ scale, const float* __restrict__ shift,
    const float* __restrict__ W1, const float* __restrict__ b1,
    const float* __restrict__ b2, const float* __restrict__ b3,
    const unsigned short* __restrict__ AbG,
    const unsigned short* __restrict__ Wt2g, const unsigned short* __restrict__ Wt3g,
    float* __restrict__ emb) {
    extern __shared__ char smem[];
    unsigned short* xb2 = (unsigned short*)smem;             // 69632 B
    unsigned short* hS2 = (unsigned short*)(smem + 69632);   // 67584 B
    float* xin2  = (float*)(smem + 137216);                  // 2832 B
    float* meanS = (float*)(smem + 140048);                  // 2048 B (end 142096)
    int tid = threadIdx.x;
    int lane = tid & 63, w = tid >> 6;
    int gr = w >> 2;
    int wl = w & 3;
    int lm = lane & 15, lq = lane >> 4;
    int wm = (wl & 1) * 64, wn = (wl >> 1) * 64;
    int g0 = blockIdx.x * 2;

    for (int i = tid; i < 4224; i += 512) ((uint4*)hS2)[i] = (uint4){0, 0, 0, 0};
    for (int i = tid; i < 2 * 10 * 64; i += 512) {
        int grr = i >= 640;
        int ii = i - grr * 640;
        int r = grr * 128 + NN + (ii >> 6), c = (ii & 63) * 2;
        *(unsigned int*)(xb2 + r * XS + c) = 0u;
    }
    float s0 = scale[0], s1 = scale[1], s2 = scale[2];
    float t0 = shift[0], t1 = shift[1], t2 = shift[2];
    for (int i = tid; i < 2 * NN * 3; i += 512) {
        int gi = (i >= NN * 3) ? 1 : 0;
        int idx = i - gi * (NN * 3);
        int f = idx % 3;
        float sc = (f == 0) ? s0 : ((f == 1) ? s1 : s2);
        float sf = (f == 0) ? t0 : ((f == 1) ? t1 : t2);
        xin2[gi * 354 + idx] = xg[(size_t)(g0 + gi) * (NN * 3) + idx] * sc + sf;
    }
    int dd = lane * 2;
    float2 w10 = *(const float2*)(W1 + dd);
    float2 w11 = *(const float2*)(W1 + DD + dd);
    float2 w12 = *(const float2*)(W1 + 2 * DD + dd);
    bar_lds();
    const float* xin = xin2 + gr * 354;
    for (int k = 0; k < 30; ++k) {
        int n = wl + 4 * k;
        if (n >= NN) break;
        float x0 = xin[n * 3], x1 = xin[n * 3 + 1], x2 = xin[n * 3 + 2];
        hS2[dd * MS + gr * 128 + n]       = f2bf(x0 * w10.x + x1 * w11.x + x2 * w12.x);
        hS2[(dd + 1) * MS + gr * 128 + n] = f2bf(x0 * w10.y + x1 * w11.y + x2 * w12.y);
    }
    bar_lds();
    mm_agg2(AbG, hS2, xb2, b1, gr, wm, wn, lm, lq);
    bar_lds();
    mm_xw2(xb2, Wt2g, hS2, gr, wm, wn, lm, lq);
    bar_lds();
    mm_agg2(AbG, hS2, xb2, b2, gr, wm, wn, lm, lq);
    bar_lds();
    mm_xw2(xb2, Wt3g, hS2, gr, wm, wn, lm, lq);
    bar_lds();
    mm_agg2(AbG, hS2, xb2, b3, gr, wm, wn, lm, lq);
    bar_lds();
    {
        int grr = tid >> 8, t2 = tid & 255;
        int part = t2 >> 7, d = t2 & 127;
        int a0 = part * 59, a1 = a0 + 59;
        float s = 0.f;
        for (int n = a0; n < a1; ++n) s += bf2f(xb2[(grr * 128 + n) * XS + d]);
        meanS[grr * 256 + part * 128 + d] = s;
    }
    bar_lds();
    if (tid < 256) {
        int grr = tid >> 7, d = tid & 127;
        float s = meanS[grr * 256 + d] + meanS[grr * 256 + 128 + d];
        emb[(size_t)(g0 + grr) * DD + d] = s * (1.0f / (float)NN);
    }
}

// ---------------------------------------------------------------------------
// proj0: dst[g][j] = bias0[j] + sum_k emb[g][k] * WT0[k][j]
// ---------------------------------------------------------------------------
__global__ __launch_bounds__(512) void proj_kernel(const float* __restrict__ src,
                                                   const float* __restrict__ WT,
                                                   const float* __restrict__ bias,
                                                   float* __restrict__ dst) {
    __shared__ __align__(16) float eL[DD];
    int g = blockIdx.x, tid = threadIdx.x;
    if (tid < DD) eL[tid] = src[(size_t)g * DD + tid];
    __syncthreads();
    float acc = bias[tid];
    const float* wt = WT + tid;
#pragma unroll 8
    for (int k = 0; k < DD; ++k) acc += eL[k] * wt[(size_t)k * FD];
    dst[(size_t)g * FD + tid] = acc;
}

// ---------------------------------------------------------------------------
// FUSED 2-layer LSTM scan (round 15). 8 blocks x 512 threads, r11 skeleton.
// 1-step skew: at step t, compute BOTH independent dots from LDS state
//   gates0(t)   = Whh0 . h0[t-1]                 (+ x0[t] from global stream)
//   gates1(t-1) = [Wih1|Whh1] . [h0[t-1];h1[t-2]] (+ bias1)
// then one combine phase updates h0[t] and h1[t-1]. 257 steps replace the
// two 256-step scans + the middle projection kernel.
// Weights: thread (quarter=j>>7, d=j&127) holds Whh0 slice (64 pairs, r11
// layout) + combined-K=256 slice (128 pairs) = 192 scalar-pinned regs
// (cap 256 at 2 waves/SIMD; watch VGPR_Count for parking regression).
// ---------------------------------------------------------------------------
__global__ __launch_bounds__(512, 2) void scan2_kernel(
    const float* __restrict__ inp0,        // [B][T][512] gates0 preact (bias0 incl)
    const unsigned int* __restrict__ Wc0,  // Whh0, r11 layout
    const unsigned int* __restrict__ Wc1,  // [Wih1|Whh1], combined layout
    const float* __restrict__ bias1,       // [512]
    float* __restrict__ hfin) {            // [B][128]
    __shared__ __align__(16) unsigned short hcat[256];  // [0..127]=h0[t-1], [128..255]=h1[t-2]
    __shared__ __align__(16) float sgP0[3 * DD * 4];
    __shared__ __align__(16) float sgP1[3 * DD * 4];
    int b = blockIdx.x, j = threadIdx.x;
    int d = j & 127, quarter = j >> 7;
    unsigned int w0[4][16], w1[4][32];
#pragma unroll
    for (int g = 0; g < 4; ++g)
#pragma unroll
        for (int q = 0; q < 16; ++q)
            w0[g][q] = Wc0[(((g * 16 + q) << 2) + quarter) * 128 + d];
#pragma unroll
    for (int g = 0; g < 4; ++g)
#pragma unroll
        for (int q = 0; q < 32; ++q)
            w1[g][q] = Wc1[(((g * 32 + q) << 2) + quarter) * 128 + d];
    // pin scalars (asm-defined values can't be rematerialized into the loop)
#pragma unroll
    for (int g = 0; g < 4; ++g) {
#pragma unroll
        for (int q = 0; q < 16; ++q) asm volatile("" : "+v"(w0[g][q]));
#pragma unroll
        for (int q = 0; q < 32; ++q) asm volatile("" : "+v"(w1[g][q]));
    }
    if (j < 128) ((unsigned int*)hcat)[j] = 0u;   // h0 = h1 = 0
    float c0 = 0.f, c1 = 0.f;
    const float* ib = inp0 + (size_t)b * TT * FD;
    float b1r[4];
    float xg0[4], xg1[4];
    if (quarter == 0) {
#pragma unroll
        for (int g = 0; g < 4; ++g) {
            b1r[g] = bias1[g * DD + d];
            xg0[g] = ib[g * DD + d];
            xg1[g] = ib[FD + g * DD + d];
        }
    }
    bar_lds();
    for (int t = 0; t <= TT; ++t) {
        float xg2[4];
        if (quarter == 0) {
            bool more = (t + 2 < TT);
#pragma unroll
            for (int g = 0; g < 4; ++g)
                xg2[g] = more ? ib[(t + 2) * FD + g * DD + d] : 0.f;  // prefetch depth 2
        }
        // dot0: Whh0 . h0 slice [32*quarter, +32)
        const uint4* h0q = (const uint4*)(hcat + quarter * 32);
        float a0 = 0.f, a1 = 0.f, a2 = 0.f, a3 = 0.f;
#pragma unroll
        for (int c = 0; c < 4; ++c) {
            uint4 hv = h0q[c];
            a0 = fdot2_(w0[0][4 * c + 0], hv.x, a0); a1 = fdot2_(w0[1][4 * c + 0], hv.x, a1);
            a2 = fdot2_(w0[2][4 * c + 0], hv.x, a2); a3 = fdot2_(w0[3][4 * c + 0], hv.x, a3);
            a0 = fdot2_(w0[0][4 * c + 1], hv.y, a0); a1 = fdot2_(w0[1][4 * c + 1], hv.y, a1);
            a2 = fdot2_(w0[2][4 * c + 1], hv.y, a2); a3 = fdot2_(w0[3][4 * c + 1], hv.y, a3);
            a0 = fdot2_(w0[0][4 * c + 2], hv.z, a0); a1 = fdot2_(w0[1][4 * c + 2], hv.z, a1);
            a2 = fdot2_(w0[2][4 * c + 2], hv.z, a2); a3 = fdot2_(w0[3][4 * c + 2], hv.z, a3);
            a0 = fdot2_(w0[0][4 * c + 3], hv.w, a0); a1 = fdot2_(w0[1][4 * c + 3], hv.w, a1);
            a2 = fdot2_(w0[2][4 * c + 3], hv.w, a2); a3 = fdot2_(w0[3][4 * c + 3], hv.w, a3);
        }
        // dot1: [Wih1|Whh1] . [h0;h1] slice [64*quarter, +64)
        const uint4* h1q = (const uint4*)(hcat + quarter * 64);
        float e0 = 0.f, e1 = 0.f, e2 = 0.f, e3 = 0.f;
#pragma unroll
        for (int c = 0; c < 8; ++c) {
            uint4 hv = h1q[c];
            e0 = fdot2_(w1[0][4 * c + 0], hv.x, e0); e1 = fdot2_(w1[1][4 * c + 0], hv.x, e1);
            e2 = fdot2_(w1[2][4 * c + 0], hv.x, e2); e3 = fdot2_(w1[3][4 * c + 0], hv.x, e3);
            e0 = fdot2_(w1[0][4 * c + 1], hv.y, e0); e1 = fdot2_(w1[1][4 * c + 1], hv.y, e1);
            e2 = fdot2_(w1[2][4 * c + 1], hv.y, e2); e3 = fdot2_(w1[3][4 * c + 1], hv.y, e3);
            e0 = fdot2_(w1[0][4 * c + 2], hv.z, e0); e1 = fdot2_(w1[1][4 * c + 2], hv.z, e1);
            e2 = fdot2_(w1[2][4 * c + 2], hv.z, e2); e3 = fdot2_(w1[3][4 * c + 2], hv.z, e3);
            e0 = fdot2_(w1[0][4 * c + 3], hv.w, e0); e1 = fdot2_(w1[1][4 * c + 3], hv.w, e1);
            e2 = fdot2_(w1[2][4 * c + 3], hv.w, e2); e3 = fdot2_(w1[3][4 * c + 3], hv.w, e3);
        }
        if (quarter != 0) {
            *(float4*)(sgP0 + ((quarter - 1) * DD + d) * 4) = make_float4(a0, a1, a2, a3);
            *(float4*)(sgP1 + ((quarter - 1) * DD + d) * 4) = make_float4(e0, e1, e2, e3);
        }
        bar_lds();
        if (quarter == 0) {
            if (t < TT) {
                float4 p1 = *(const float4*)(sgP0 + d * 4);
                float4 p2 = *(const float4*)(sgP0 + (DD + d) * 4);
                float4 p3 = *(const float4*)(sgP0 + (2 * DD + d) * 4);
                float iv = sig_f(a0 + p1.x + p2.x + p3.x + xg0[0]);
                float fv = sig_f(a1 + p1.y + p2.y + p3.y + xg0[1]);
                float gv = tanh_f(a2 + p1.z + p2.z + p3.z + xg0[2]);
                float ov = sig_f(a3 + p1.w + p2.w + p3.w + xg0[3]);
                float cn = fv * c0 + iv * gv;
                c0 = cn;
                ((_Float16*)hcat)[d] = (_Float16)(ov * tanh_f(cn));   // h0[t]
            }
            if (t >= 1) {
                float4 q1 = *(const float4*)(sgP1 + d * 4);
                float4 q2 = *(const float4*)(sgP1 + (DD + d) * 4);
                float4 q3 = *(const float4*)(sgP1 + (2 * DD + d) * 4);
                float iv = sig_f(e0 + q1.x + q2.x + q3.x + b1r[0]);
                float fv = sig_f(e1 + q1.y + q2.y + q3.y + b1r[1]);
                float gv = tanh_f(e2 + q1.z + q2.z + q3.z + b1r[2]);
                float ov = sig_f(e3 + q1.w + q2.w + q3.w + b1r[3]);
                float cn = fv * c1 + iv * gv;
                c1 = cn;
                float hn = ov * tanh_f(cn);
                ((_Float16*)hcat)[128 + d] = (_Float16)hn;            // h1[t-1]
                if (t == TT) hfin[b * DD + d] = hn;                   // final h1[TT-1]
            }
#pragma unroll
            for (int g = 0; g < 4; ++g) { xg0[g] = xg1[g]; xg1[g] = xg2[g]; }
        }
        bar_lds();
    }
}

// ---------------------------------------------------------------------------
// head MLP on final hidden state. 1 block.
// ---------------------------------------------------------------------------
__global__ void head_kernel(const float* __restrict__ hfin,
                            const float* __restrict__ hW1, const float* __restrict__ hb1,
                            const float* __restrict__ hW2, const float* __restrict__ hb2,
                            const float* __restrict__ hW3, const float* __restrict__ hb3,
                            float* __restrict__ out) {
    __shared__ float fh[BB * DD];
    __shared__ float y1[BB * DD];
    __shared__ float y2[BB * 64];
    int tid = threadIdx.x;
    for (int i = tid; i < BB * DD; i += 256) fh[i] = hfin[i];
    __syncthreads();
    for (int i = tid; i < BB * DD; i += 256) {
        int bb = i >> 7, jj = i & 127;
        float acc = hb1[jj];
        for (int k = 0; k < DD; ++k) acc += fh[(bb << 7) + k] * hW1[(k << 7) + jj];
        y1[i] = siluf_(acc);
    }
    __syncthreads();
    for (int i = tid; i < BB * 64; i += 256) {
        int bb = i >> 6, jj = i & 63;
        float acc = hb2[jj];
        for (int k = 0; k < DD; ++k) acc += y1[(bb << 7) + k] * hW2[(k << 6) + jj];
        y2[i] = siluf_(acc);
    }
    __syncthreads();
    if (tid < BB * 2) {
        int bb = tid >> 1, m = tid & 1;
        float acc = hb3[m];
        for (int k = 0; k < 64; ++k) acc += y2[(bb << 6) + k] * hW3[k * 2 + m];
        float sp = fmaxf(acc, 0.f) + log1pf(expf(-fabsf(acc)));
        out[tid] = sp + 1e-6f;
    }
}

// ---------------------------------------------------------------------------
extern "C" void kernel_launch(void* const* d_in, const int* in_sizes, int n_in,
                              void* d_out, int out_size, void* d_ws, size_t ws_size,
                              hipStream_t stream) {
    const float* snap  = (const float*)d_in[0];
    const int*   edges = (const int*)d_in[1];
    const float* scale = (const float*)d_in[2];
    const float* shift = (const float*)d_in[3];
    const float* W1 = (const float*)d_in[4];
    const float* b1 = (const float*)d_in[5];
    const float* W2 = (const float*)d_in[6];
    const float* b2 = (const float*)d_in[7];
    const float* W3 = (const float*)d_in[8];
    const float* b3 = (const float*)d_in[9];
    const float* Wih0 = (const float*)d_in[10];
    const float* Whh0 = (const float*)d_in[11];
    const float* bih0 = (const float*)d_in[12];
    const float* bhh0 = (const float*)d_in[13];
    const float* Wih1 = (const float*)d_in[14];
    const float* Whh1 = (const float*)d_in[15];
    const float* bih1 = (const float*)d_in[16];
    const float* bhh1 = (const float*)d_in[17];
    const float* hW1 = (const float*)d_in[18];
    const float* hb1 = (const float*)d_in[19];
    const float* hW2 = (const float*)d_in[20];
    const float* hb2 = (const float*)d_in[21];
    const float* hW3 = (const float*)d_in[22];
    const float* hb3 = (const float*)d_in[23];

    // workspace carve (float indices); ~6.1 MB
    float* ws = (float*)d_ws;
    float* bias0 = ws + 0;                        // 512
    float* bias1 = ws + 512;                      // 512
    unsigned short* AbG  = (unsigned short*)(ws + 1024);   // 8192 f
    unsigned short* Wt2g = (unsigned short*)(ws + 9216);   // 8192 f
    unsigned short* Wt3g = (unsigned short*)(ws + 17408);  // 8192 f
    float* WT0 = ws + 25600;                      // 65536
    unsigned int* Wc0 = (unsigned int*)(ws + 91136);       // 32768
    unsigned int* Wc1 = (unsigned int*)(ws + 123904);      // 65536
    float* emb  = ws + 189440;                    // 262144
    float* inp  = ws + 451584;                    // 1048576
    float* hfin = ws + 1500160;                   // 1024

    const int smem_gcn = 142096;
    hipFuncSetAttribute((const void*)gcn_kernel,
                        hipFuncAttributeMaxDynamicSharedMemorySize, smem_gcn);

    prep_kernel<<<1, 256, 0, stream>>>(edges, bih0, bhh0, bih1, bhh1,
                                       bias0, bias1, AbG);
    convall_kernel<<<384, 512, 0, stream>>>(W2, W3, Whh0, Wih1, Whh1, Wih0,
                                            Wt2g, Wt3g, Wc0, Wc1, WT0);
    gcn_kernel<<<GG / 2, 512, smem_gcn, stream>>>(snap, scale, shift, W1, b1, b2, b3,
                                                  AbG, Wt2g, Wt3g, emb);
    proj_kernel<<<GG, 512, 0, stream>>>(emb, WT0, bias0, inp);
    scan2_kernel<<<BB, 512, 0, stream>>>(inp, Wc0, Wc1, bias1, hfin);
    head_kernel<<<1, 256, 0, stream>>>(hfin, hW1, hb1, hW2, hb2, hW3, hb3, (float*)d_out);
}